// Round 10
// baseline (342.504 us; speedup 1.0000x reference)
//
#include <hip/hip_runtime.h>
#include <cstdint>
#include <cstddef>

#define T_TOK 64
#define K_IN 4096
#define N_OUT 14336
#define SPLITK 16
#define KCHUNK 256                   // K per block (4096/16)
#define NSTAGES 8                    // 8 stages x 32 k
#define NCOLS 64                     // cols per block (16 per wave)

typedef __attribute__((ext_vector_type(8))) short bf16x8;
typedef __attribute__((ext_vector_type(4))) float f32x4;

static __device__ __forceinline__ unsigned short bf16_rne(float f) {
    unsigned u = __builtin_bit_cast(unsigned, f);
    unsigned r = (u + 0x7fffu + ((u >> 16) & 1u)) >> 16;
    return (unsigned short)r;
}

// Kernel 1: x (fp32) -> bf16 copy in ws + per-token row sums.
__global__ __launch_bounds__(256) void prep_kernel(const float* __restrict__ x,
                                                   unsigned short* __restrict__ xbf,
                                                   float* __restrict__ rowsum) {
    const int row = blockIdx.x;
    const int t = threadIdx.x;
    const float4* x4 = (const float4*)(x + (size_t)row * K_IN);
    float s = 0.f;
#pragma unroll
    for (int i = 0; i < 4; i++) {
        float4 v = x4[i * 256 + t];
        s += v.x + v.y + v.z + v.w;
        ushort4 h;
        h.x = bf16_rne(v.x); h.y = bf16_rne(v.y);
        h.z = bf16_rne(v.z); h.w = bf16_rne(v.w);
        *(ushort4*)(xbf + (size_t)row * K_IN + (size_t)(i * 256 + t) * 4) = h;
    }
#pragma unroll
    for (int off = 32; off > 0; off >>= 1) s += __shfl_down(s, off, 64);
    __shared__ float part[4];
    const int wave = t >> 6, lane = t & 63;
    if (lane == 0) part[wave] = s;
    __syncthreads();
    if (t == 0) rowsum[row] = part[0] + part[1] + part[2] + part[3];
}

// Kernel 2: initialize out with bias + rowsum*u. Grid (N_OUT/4/256, T_TOK).
__global__ __launch_bounds__(256) void init_kernel(const float* __restrict__ rowsum,
                                                   const float* __restrict__ u,
                                                   const float* __restrict__ bias,
                                                   float* __restrict__ out) {
    const int t = blockIdx.y;
    const int n4 = blockIdx.x * 256 + threadIdx.x;
    const float rs = rowsum[t];
    float4 b = ((const float4*)bias)[n4];
    float4 uu = ((const float4*)u)[n4];
    float4 o;
    o.x = b.x + rs * uu.x; o.y = b.y + rs * uu.y;
    o.z = b.z + rs * uu.z; o.w = b.w + rs * uu.w;
    ((float4*)(out + (size_t)t * N_OUT))[n4] = o;
}

// ---- manual-pipeline primitives: inline-asm loads + inline-asm vmcnt waits.
// The compiler's waitcnt pass does not track asm loads, so it cannot insert
// the conservative vmcnt(0) that killed rounds 8/9. The WAIT_B "+v" ties make
// every consumer data-dependent on the wait.
#define LOAD_B(dst, p) \
    asm volatile("global_load_dword %0, %1, off" : "=v"(dst) : "v"(p))

#define WAIT_B(cnt, B) \
    asm volatile("s_waitcnt vmcnt(" #cnt ")" \
        : "+v"((B)[0]), "+v"((B)[1]), "+v"((B)[2]), "+v"((B)[3]), \
          "+v"((B)[4]), "+v"((B)[5]), "+v"((B)[6]), "+v"((B)[7]))

#define ISSUE_B(S, B) \
    { \
        LOAD_B((B)[0], wlane + (size_t)((S) * 32 + 0) * N_OUT); \
        LOAD_B((B)[1], wlane + (size_t)((S) * 32 + 1) * N_OUT); \
        LOAD_B((B)[2], wlane + (size_t)((S) * 32 + 2) * N_OUT); \
        LOAD_B((B)[3], wlane + (size_t)((S) * 32 + 3) * N_OUT); \
        LOAD_B((B)[4], wlane + (size_t)((S) * 32 + 4) * N_OUT); \
        LOAD_B((B)[5], wlane + (size_t)((S) * 32 + 5) * N_OUT); \
        LOAD_B((B)[6], wlane + (size_t)((S) * 32 + 6) * N_OUT); \
        LOAD_B((B)[7], wlane + (size_t)((S) * 32 + 7) * N_OUT); \
    }

// Kernel 3: split-K int4-dequant GEMM, manual register pipeline for B.
// Grid (224, 16) x 256 thr. Wave owns a 16-col strip x 64 tokens x 256 k.
// B: per-lane dword asm loads (lane(q,r) -> W[k=q*8+j][col r]; 4x64B segments
// per instr), depth-2 double buffer, 16 dwords in flight/lane = 4 KB/wave;
// 12 waves/CU -> ~48 KB/CU in flight > BDP. Waits are asm vmcnt(8)/(0).
// A: 64x256 bf16 (32 KB) staged to LDS once, XOR-swizzled; one barrier total.
__global__ __launch_bounds__(256, 3) void gemm_kernel(const unsigned short* __restrict__ xbf,
                                                      const int* __restrict__ W,
                                                      const float* __restrict__ scales,
                                                      float* __restrict__ out) {
    __shared__ char Alds[32768];

    const int tid = threadIdx.x;
    const int wave = tid >> 6;
    const int lane = tid & 63;
    const int q = lane >> 4;            // quad: k-offset q*8 in frags
    const int r = lane & 15;            // col within wave strip / token row
    const int cb = blockIdx.x;
    const int kbase = blockIdx.y * KCHUNK;
    const int col = cb * NCOLS + wave * 16 + r;

    // two 128-group scales covering this block's 256-k chunk (loaded before
    // the barrier so their waitcnt is folded into the barrier's drain)
    const int g0 = kbase >> 7;
    float sc0 = scales[(size_t)g0 * N_OUT + col];
    float sc1 = scales[(size_t)(g0 + 1) * N_OUT + col];
    asm volatile("" : "+v"(sc0), "+v"(sc1));   // pin: materialized pre-barrier

    // ---- stage A once: 64 rows x 512 B, 16-B chunk cc stored at cc^(row&7)
    {
        int4 av[8];
#pragma unroll
        for (int i = 0; i < 8; i++) {
            const int chunk = i * 256 + tid;           // 2048 chunks of 16 B
            const int row = chunk >> 5;
            const int cc = chunk & 31;
            av[i] = *(const int4*)(xbf + (size_t)row * K_IN + kbase + cc * 8);
        }
#pragma unroll
        for (int i = 0; i < 8; i++) {
            const int chunk = i * 256 + tid;
            const int row = chunk >> 5;
            const int cc = chunk & 31;
            *(int4*)(Alds + row * 512 + (cc ^ (row & 7)) * 16) = av[i];
        }
    }
    __syncthreads();   // ONLY barrier: A visible; all compiler vmem drained

    const int* wlane = W + (size_t)(kbase + q * 8) * N_OUT + col;

    f32x4 acc[4];
#pragma unroll
    for (int mt = 0; mt < 4; mt++) acc[mt] = f32x4{0.f, 0.f, 0.f, 0.f};

    // consume one 32-k stage: dequant 8 ints -> bf16 frag, 4 MFMAs vs A tiles
    auto consume = [&](int s, int (&B)[8]) {
        const float scs = (s < 4) ? sc0 : sc1;        // group = (kbase+s*32)/128
        bf16x8 bf;
#pragma unroll
        for (int j = 0; j < 8; j++) bf[j] = (short)bf16_rne((float)B[j] * scs);
#pragma unroll
        for (int mt = 0; mt < 4; mt++) {
            const int row = r + mt * 16;
            bf16x8 af = *(const bf16x8*)(Alds + row * 512 + (((s * 4 + q) ^ (r & 7)) << 4));
            acc[mt] = __builtin_amdgcn_mfma_f32_16x16x32_bf16(af, bf, acc[mt], 0, 0, 0);
        }
    };

    int b0[8], b1[8];
    ISSUE_B(0, b0); ISSUE_B(1, b1);
    WAIT_B(8, b0); consume(0, b0); ISSUE_B(2, b0);
    WAIT_B(8, b1); consume(1, b1); ISSUE_B(3, b1);
    WAIT_B(8, b0); consume(2, b0); ISSUE_B(4, b0);
    WAIT_B(8, b1); consume(3, b1); ISSUE_B(5, b1);
    WAIT_B(8, b0); consume(4, b0); ISSUE_B(6, b0);
    WAIT_B(8, b1); consume(5, b1); ISSUE_B(7, b1);
    WAIT_B(8, b0); consume(6, b0);
    WAIT_B(0, b1); consume(7, b1);

    // epilogue: atomic accumulate partials (C/D layout: row = q*4+i, col = col)
#pragma unroll
    for (int mt = 0; mt < 4; mt++) {
#pragma unroll
        for (int i = 0; i < 4; i++) {
            const int t = mt * 16 + q * 4 + i;
            atomicAdd(out + (size_t)t * N_OUT + col, acc[mt][i]);
        }
    }
}

extern "C" void kernel_launch(void* const* d_in, const int* in_sizes, int n_in,
                              void* d_out, int out_size, void* d_ws, size_t ws_size,
                              hipStream_t stream) {
    const float* x      = (const float*)d_in[0];
    const int*   W      = (const int*)d_in[1];
    const float* scales = (const float*)d_in[2];
    const float* u      = (const float*)d_in[3];
    const float* bias   = (const float*)d_in[4];
    float* out = (float*)d_out;

    unsigned short* xbf = (unsigned short*)d_ws;                        // 64*4096*2 = 512 KB
    float* rowsum = (float*)((char*)d_ws + (size_t)T_TOK * K_IN * 2);   // 64 floats

    prep_kernel<<<T_TOK, 256, 0, stream>>>(x, xbf, rowsum);
    init_kernel<<<dim3(N_OUT / 4 / 256, T_TOK), 256, 0, stream>>>(rowsum, u, bias, out);
    gemm_kernel<<<dim3(N_OUT / NCOLS, SPLITK), 256, 0, stream>>>(xbf, W, scales, out);
}